// Round 3
// baseline (18712.791 us; speedup 1.0000x reference)
//
#include <hip/hip_runtime.h>
#include <math.h>

// ===== problem constants (washout hardcoded=200 per reference) =====
#define NH      2048
#define TT      4096
#define DIN     64
#define WASH    200
#define TW      (TT - WASH)      // 3896
#define LAMBDA  1e-6f

#define SCAN_BLOCKS  256
#define CG_BLOCKS    256
#define CG_ITERS     400

typedef unsigned long long u64;

// ===== workspace layout =====
// floats:
#define X_OFF      ((size_t)0)                 // TT*NH (32 MB)
#define DRIVE_OFF  ((size_t)TT * NH)           // TT*NH (dead after scan)
#define A_OFF      DRIVE_OFF                   // NH*NH aliases drive
#define B_OFF      ((size_t)2 * TT * NH)       // NH
#define INVD_OFF   (B_OFF + NH)                // NH
#define XV_OFF     (INVD_OFF + NH)             // NH (Wout)
#define WS_FLOATS  (XV_OFF + NH)               // even -> u64 area stays 8B-aligned
// u64s (at ws + WS_FLOATS):
#define XPACK_OFF  ((size_t)0)                 // 2*NH  (double-buffered packed x)
#define PPACK_OFF  ((size_t)2 * NH)            // NH    (packed p)
#define PQS_OFF    ((size_t)3 * NH)            // 256   (packed pq partials)
#define RHOS_OFF   ((size_t)3 * NH + 256)      // 256   (packed rho partials)
#define U64_TOTAL  ((size_t)3 * NH + 512)

__device__ __forceinline__ u64 pack_ev(int epoch, float v) {
    return ((u64)(unsigned)epoch << 32) | (u64)__float_as_uint(v);
}
__device__ __forceinline__ int  ep_of(u64 p) { return (int)(p >> 32); }
__device__ __forceinline__ float val_of(u64 p) { return __uint_as_float((unsigned)p); }

__device__ __forceinline__ u64 aload(const u64* p) {
    return __hip_atomic_load(p, __ATOMIC_RELAXED, __HIP_MEMORY_SCOPE_AGENT);
}
__device__ __forceinline__ void astore(u64* p, u64 v) {
    __hip_atomic_store(p, v, __ATOMIC_RELAXED, __HIP_MEMORY_SCOPE_AGENT);
}

// ===== init: zero packed slots + bvec =====
__global__ void init_kernel(float* ws) {
    int tid = threadIdx.x;
    u64* ub = (u64*)(ws + WS_FLOATS);
    for (size_t i = tid; i < U64_TOTAL; i += 256) ub[i] = 0ull;
    for (int i = tid; i < NH; i += 256) ws[B_OFF + i] = 0.f;
}

// ===== drive = u @ W_in.T =====
__global__ __launch_bounds__(256) void drive_kernel(
    const float* __restrict__ u, const float* __restrict__ Win,
    float* __restrict__ drive)
{
    __shared__ float Wt[256 * 64];
    const int tid = threadIdx.x;
    const int ic = blockIdx.x & 7;
    const int tc = blockIdx.x >> 3;
    const int i0 = ic * 256;
    for (int idx = tid; idx < 256 * 64; idx += 256) {
        int il = idx >> 6, k = idx & 63;
        Wt[k * 256 + il] = Win[(size_t)i0 * 64 + idx];
    }
    __syncthreads();
    for (int tt_ = 0; tt_ < 128; ++tt_) {
        int t = tc * 128 + tt_;
        const float* ur = u + (size_t)t * DIN;
        float acc = 0.f;
        #pragma unroll
        for (int k = 0; k < 64; ++k)
            acc = fmaf(Wt[k * 256 + tid], ur[k], acc);
        drive[(size_t)t * NH + i0 + tid] = acc;
    }
}

// ===== the scan: packed epoch+value publish, single-hop sync =====
__global__ __launch_bounds__(256, 1) void scan_kernel(
    const float* __restrict__ W, const float* __restrict__ drive,
    float* __restrict__ X, u64* xpack)
{
    __shared__ float xls[NH];        // 8 KB
    const int tid     = threadIdx.x;
    const int r_local = tid >> 5;    // 8 rows/block, 32 lanes per row
    const int lane32  = tid & 31;
    const int row     = blockIdx.x * 8 + r_local;

    float4 wreg[16];                 // W[row][lane32*4 + 128j ..]
    {
        const float* wp = W + (size_t)row * NH + lane32 * 4;
        #pragma unroll
        for (int j = 0; j < 16; ++j) wreg[j] = *(const float4*)(wp + 128 * j);
    }

    for (int t = 0; t < TT; ++t) {
        float dval = drive[(size_t)t * NH + row];   // independent prefetch

        if (t == 0) {
            #pragma unroll
            for (int k = 0; k < 8; ++k) xls[tid + 256 * k] = 0.f;
        } else {
            const u64* src = xpack + (size_t)((t - 1) & 1) * NH;
            const int want = t;      // step t-1 published with epoch t
            u64 pk[8];
            #pragma unroll
            for (int k = 0; k < 8; ++k) pk[k] = aload(&src[tid + 256 * k]);
            unsigned pend = 0;
            #pragma unroll
            for (int k = 0; k < 8; ++k) {
                if (ep_of(pk[k]) >= want) xls[tid + 256 * k] = val_of(pk[k]);
                else pend |= (1u << k);
            }
            while (pend) {
                __builtin_amdgcn_s_sleep(1);
                #pragma unroll
                for (int k = 0; k < 8; ++k) if (pend & (1u << k)) {
                    u64 v = aload(&src[tid + 256 * k]);
                    if (ep_of(v) >= want) {
                        xls[tid + 256 * k] = val_of(v);
                        pend &= ~(1u << k);
                    }
                }
            }
        }
        __syncthreads();

        float acc = 0.f;
        #pragma unroll
        for (int j = 0; j < 16; ++j) {
            float4 xv4 = *(const float4*)&xls[lane32 * 4 + 128 * j];
            float4 wv = wreg[j];
            acc = fmaf(wv.x, xv4.x, fmaf(wv.y, xv4.y,
                  fmaf(wv.z, xv4.z, fmaf(wv.w, xv4.w, acc))));
        }
        #pragma unroll
        for (int m = 16; m; m >>= 1) acc += __shfl_xor(acc, m);

        if (lane32 == 0) {
            float v = tanhf(acc + dval);
            X[(size_t)t * NH + row] = v;                 // for gram/bvec/out
            astore(&xpack[(size_t)(t & 1) * NH + row], pack_ev(t + 1, v));
        }
        __syncthreads();   // xls stable until all reads done
    }
}

// ===== A = Xw^T Xw + lambda*I =====
__global__ __launch_bounds__(256) void gram_kernel(
    const float* __restrict__ X, float* __restrict__ A)
{
    __shared__ float As[16 * 64];
    __shared__ float Bs[16 * 64];
    const int tx = threadIdx.x, ty = threadIdx.y;
    const int tid = ty * 16 + tx;
    const int i0 = blockIdx.y * 64, j0 = blockIdx.x * 64;
    const int ty4 = ty * 4, tx4 = tx * 4;
    float acc[4][4] = {};

    const int nch = (TW + 15) / 16;
    for (int ch = 0; ch < nch; ++ch) {
        int tbase = WASH + ch * 16;
        for (int v = tid; v < 16 * 64; v += 256) {
            int kk = v >> 6, col = v & 63;
            int t = tbase + kk;
            float a_ = 0.f, b_ = 0.f;
            if (t < TT) {
                a_ = X[(size_t)t * NH + i0 + col];
                b_ = X[(size_t)t * NH + j0 + col];
            }
            As[v] = a_; Bs[v] = b_;
        }
        __syncthreads();
        #pragma unroll
        for (int k = 0; k < 16; ++k) {
            float4 av = *(const float4*)&As[k * 64 + ty4];
            float4 bv = *(const float4*)&Bs[k * 64 + tx4];
            float a[4] = {av.x, av.y, av.z, av.w};
            float b[4] = {bv.x, bv.y, bv.z, bv.w};
            #pragma unroll
            for (int ai = 0; ai < 4; ++ai)
                #pragma unroll
                for (int bi = 0; bi < 4; ++bi)
                    acc[ai][bi] = fmaf(a[ai], b[bi], acc[ai][bi]);
        }
        __syncthreads();
    }
    #pragma unroll
    for (int ai = 0; ai < 4; ++ai) {
        int gi = i0 + ty4 + ai;
        #pragma unroll
        for (int bi = 0; bi < 4; ++bi) {
            int gj = j0 + tx4 + bi;
            float v = acc[ai][bi];
            if (gi == gj) v += LAMBDA;
            A[(size_t)gi * NH + gj] = v;
        }
    }
}

// ===== b = Xw^T yw : 64 blocks (8 i-chunks x 8 t-chunks) =====
__global__ void bvec_kernel(const float* __restrict__ X, const float* __restrict__ y,
                            float* __restrict__ bv)
{
    const int ic = blockIdx.x & 7, tc = blockIdx.x >> 3;
    const int i = ic * 256 + threadIdx.x;
    const int t0 = WASH + tc * (TW / 8), t1 = t0 + (TW / 8);
    float acc = 0.f;
    for (int t = t0; t < t1; ++t)
        acc = fmaf(X[(size_t)t * NH + i], y[t], acc);
    atomicAdd(&bv[i], acc);
}

__global__ void invdiag_kernel(const float* __restrict__ A, float* __restrict__ invd)
{
    int i = blockIdx.x * 256 + threadIdx.x;
    invd[i] = 1.0f / A[(size_t)i * NH + i];
}

// deterministic block-wide sum of slot values (identical order in every block)
__device__ __forceinline__ float slot_poll_sum(const u64* slots, int want, float* red)
{
    const int tid = threadIdx.x;
    u64 v = aload(&slots[tid]);
    while (ep_of(v) < want) {
        __builtin_amdgcn_s_sleep(1);
        v = aload(&slots[tid]);
    }
    float x = val_of(v);
    #pragma unroll
    for (int m = 32; m; m >>= 1) x += __shfl_xor(x, m);
    __syncthreads();                       // red[] free for reuse
    if ((tid & 63) == 0) red[tid >> 6] = x;
    __syncthreads();
    return (red[0] + red[1]) + (red[2] + red[3]);
}

// ===== Jacobi-preconditioned CG: 256 blocks, 8 rows/block, zero explicit barriers =====
__global__ __launch_bounds__(256, 1) void cg_kernel(
    const float* __restrict__ A, const float* __restrict__ bvec,
    const float* __restrict__ invd, float* __restrict__ xv,
    u64* ppack, u64* pqs, u64* rhos)
{
    __shared__ float pls[NH];        // 8 KB
    __shared__ float red[4];
    __shared__ float r8[8], x8[8], q8[8], z8[8], red8[8];
    const int tid     = threadIdx.x;
    const int r_local = tid >> 5;
    const int lane32  = tid & 31;
    const int row0 = blockIdx.x * 8;
    const int row  = row0 + r_local;
    const float* arow = A + (size_t)row * NH + lane32 * 4;

    // init: x=0, r=b, z=M^-1 r, p=z (epoch 1); rho0 partial (epoch 1)
    if (tid < 8) {
        int i = row0 + tid;
        float bi = bvec[i];
        x8[tid] = 0.f; r8[tid] = bi;
        float zi = invd[i] * bi;
        z8[tid] = zi;
        astore(&ppack[i], pack_ev(1, zi));
        red8[tid] = bi * zi;
    }
    __syncthreads();
    if (tid == 0) {
        float s = 0.f;
        #pragma unroll
        for (int k = 0; k < 8; ++k) s += red8[k];
        astore(&rhos[blockIdx.x], pack_ev(1, s));
    }
    float rho_cur = slot_poll_sum(rhos, 1, red);

    for (int it = 0; it < CG_ITERS; ++it) {
        // A rows into regs (L2-resident after iter 0) while p arrives
        float4 areg[16];
        #pragma unroll
        for (int j = 0; j < 16; ++j) areg[j] = *(const float4*)(arow + 128 * j);

        // gather p (epoch it+1) into LDS
        {
            const int want = it + 1;
            u64 pk[8];
            #pragma unroll
            for (int k = 0; k < 8; ++k) pk[k] = aload(&ppack[tid + 256 * k]);
            unsigned pend = 0;
            #pragma unroll
            for (int k = 0; k < 8; ++k) {
                if (ep_of(pk[k]) >= want) pls[tid + 256 * k] = val_of(pk[k]);
                else pend |= (1u << k);
            }
            while (pend) {
                __builtin_amdgcn_s_sleep(1);
                #pragma unroll
                for (int k = 0; k < 8; ++k) if (pend & (1u << k)) {
                    u64 v = aload(&ppack[tid + 256 * k]);
                    if (ep_of(v) >= want) {
                        pls[tid + 256 * k] = val_of(v);
                        pend &= ~(1u << k);
                    }
                }
            }
        }
        __syncthreads();

        // q = A p (rows row0..row0+7), pq partial
        float acc = 0.f;
        #pragma unroll
        for (int j = 0; j < 16; ++j) {
            float4 pv = *(const float4*)&pls[lane32 * 4 + 128 * j];
            float4 av = areg[j];
            acc = fmaf(av.x, pv.x, fmaf(av.y, pv.y,
                  fmaf(av.z, pv.z, fmaf(av.w, pv.w, acc))));
        }
        #pragma unroll
        for (int m = 16; m; m >>= 1) acc += __shfl_xor(acc, m);
        if (lane32 == 0) {
            q8[r_local] = acc;
            red8[r_local] = acc * pls[row];
        }
        __syncthreads();
        if (tid == 0) {
            float s = 0.f;
            #pragma unroll
            for (int k = 0; k < 8; ++k) s += red8[k];
            astore(&pqs[blockIdx.x], pack_ev(it + 1, s));
        }
        float pq_sum = slot_poll_sum(pqs, it + 1, red);
        float alpha = (pq_sum != 0.f) ? rho_cur / pq_sum : 0.f;

        // x,r,z updates + rho partial
        if (tid < 8) {
            int k = tid, i = row0 + k;
            float pi = pls[i];
            float xi = x8[k] + alpha * pi;
            float ri = r8[k] - alpha * q8[k];
            x8[k] = xi; r8[k] = ri;
            float zi = invd[i] * ri;
            z8[k] = zi;
            red8[k] = ri * zi;
        }
        __syncthreads();
        if (tid == 0) {
            float s = 0.f;
            #pragma unroll
            for (int k = 0; k < 8; ++k) s += red8[k];
            astore(&rhos[blockIdx.x], pack_ev(it + 2, s));
        }
        float rho_new = slot_poll_sum(rhos, it + 2, red);
        float beta = (rho_cur != 0.f) ? rho_new / rho_cur : 0.f;
        rho_cur = rho_new;

        // p update (epoch it+2)
        if (tid < 8) {
            int k = tid, i = row0 + k;
            float pn = z8[k] + beta * pls[i];
            astore(&ppack[i], pack_ev(it + 2, pn));
        }
        __syncthreads();   // pls/q8/red8 stable until all uses done
    }

    if (tid < 8) xv[row0 + tid] = x8[tid];
}

// ===== out = Xw @ Wout =====
__global__ void out_kernel(const float* __restrict__ X, const float* __restrict__ w,
                           float* __restrict__ out)
{
    __shared__ float red[4];
    const int tid = threadIdx.x;
    const int rowt = WASH + blockIdx.x;
    float acc = 0.f;
    #pragma unroll
    for (int j = 0; j < 8; ++j) {
        int c = tid + 256 * j;
        acc = fmaf(X[(size_t)rowt * NH + c], w[c], acc);
    }
    #pragma unroll
    for (int m = 32; m; m >>= 1) acc += __shfl_xor(acc, m);
    if ((tid & 63) == 0) red[tid >> 6] = acc;
    __syncthreads();
    if (tid == 0) out[blockIdx.x] = red[0] + red[1] + red[2] + red[3];
}

extern "C" void kernel_launch(void* const* d_in, const int* in_sizes, int n_in,
                              void* d_out, int out_size, void* d_ws, size_t ws_size,
                              hipStream_t stream)
{
    const float* u    = (const float*)d_in[0];   // (4096, 64)
    const float* y    = (const float*)d_in[1];   // (4096, 1)
    const float* Win  = (const float*)d_in[2];   // (2048, 64)
    const float* Wres = (const float*)d_in[3];   // (2048, 2048)
    // d_in[4] = washout (==200), hardcoded as WASH

    float* ws = (float*)d_ws;
    float* X     = ws + X_OFF;
    float* drive = ws + DRIVE_OFF;
    float* A     = ws + A_OFF;
    u64*   ub    = (u64*)(ws + WS_FLOATS);
    u64*   xpack = ub + XPACK_OFF;
    u64*   ppack = ub + PPACK_OFF;
    u64*   pqs   = ub + PQS_OFF;
    u64*   rhos  = ub + RHOS_OFF;

    init_kernel<<<1, 256, 0, stream>>>(ws);
    drive_kernel<<<256, 256, 0, stream>>>(u, Win, drive);
    scan_kernel<<<SCAN_BLOCKS, 256, 0, stream>>>(Wres, drive, X, xpack);
    gram_kernel<<<dim3(32, 32), dim3(16, 16), 0, stream>>>(X, A);
    bvec_kernel<<<64, 256, 0, stream>>>(X, y, ws + B_OFF);
    invdiag_kernel<<<8, 256, 0, stream>>>(A, ws + INVD_OFF);
    cg_kernel<<<CG_BLOCKS, 256, 0, stream>>>(A, ws + B_OFF, ws + INVD_OFF,
                                             ws + XV_OFF, ppack, pqs, rhos);
    out_kernel<<<TW, 256, 0, stream>>>(X, ws + XV_OFF, (float*)d_out);
}

// Round 5
// 14500.278 us; speedup vs baseline: 1.2905x; 1.2905x over previous
//
#include <hip/hip_runtime.h>
#include <math.h>

// ===== problem constants (washout hardcoded=200 per reference) =====
#define NH      2048
#define TT      4096
#define DIN     64
#define WASH    200
#define TW      (TT - WASH)      // 3896
#define LAMBDA  1e-6f

#define SCAN_BLOCKS  64          // 32 rows/block, 1024 threads
#define CG_BLOCKS    64
#define CG_ITERS     400

typedef unsigned long long u64;

// ===== workspace layout =====
// floats:
#define X_OFF      ((size_t)0)                 // TT*NH (32 MB)
#define DRIVE_OFF  ((size_t)TT * NH)           // TT*NH (dead after scan)
#define A_OFF      DRIVE_OFF                   // NH*NH aliases drive
#define B_OFF      ((size_t)2 * TT * NH)       // NH
#define INVD_OFF   (B_OFF + NH)                // NH
#define XV_OFF     (INVD_OFF + NH)             // NH (Wout)
#define WS_FLOATS  (XV_OFF + NH)               // even -> u64 area 8B-aligned
// u64s (at ws + WS_FLOATS):
#define XPACK_OFF  ((size_t)0)                 // 2*NH (double-buffered packed x)
#define PPACK_OFF  ((size_t)2 * NH)            // NH   (packed p)
#define PQSLOT_OFF ((size_t)3 * NH)            // 64   ((p,q) partials)
#define RZSLOT_OFF ((size_t)3 * NH + 64)       // 64   ((r,z) partials; also rho0)
#define U64_TOTAL  ((size_t)3 * NH + 128)

__device__ __forceinline__ u64 pack_ev(int epoch, float v) {
    return ((u64)(unsigned)epoch << 32) | (u64)__float_as_uint(v);
}
__device__ __forceinline__ int   ep_of(u64 p)  { return (int)(p >> 32); }
__device__ __forceinline__ float val_of(u64 p) { return __uint_as_float((unsigned)p); }

__device__ __forceinline__ u64 aload(const u64* p) {
    return __hip_atomic_load(p, __ATOMIC_RELAXED, __HIP_MEMORY_SCOPE_AGENT);
}
__device__ __forceinline__ void astore(u64* p, u64 v) {
    __hip_atomic_store(p, v, __ATOMIC_RELAXED, __HIP_MEMORY_SCOPE_AGENT);
}

// ===== init =====
__global__ void init_kernel(float* ws) {
    int tid = threadIdx.x;
    u64* ub = (u64*)(ws + WS_FLOATS);
    for (size_t i = tid; i < U64_TOTAL; i += 256) ub[i] = 0ull;
    for (int i = tid; i < NH; i += 256) ws[B_OFF + i] = 0.f;
}

// ===== drive = u @ W_in.T =====
__global__ __launch_bounds__(256) void drive_kernel(
    const float* __restrict__ u, const float* __restrict__ Win,
    float* __restrict__ drive)
{
    __shared__ float Wt[256 * 64];
    const int tid = threadIdx.x;
    const int ic = blockIdx.x & 7;
    const int tc = blockIdx.x >> 3;
    const int i0 = ic * 256;
    for (int idx = tid; idx < 256 * 64; idx += 256) {
        int il = idx >> 6, k = idx & 63;
        Wt[k * 256 + il] = Win[(size_t)i0 * 64 + idx];
    }
    __syncthreads();
    for (int tt_ = 0; tt_ < 128; ++tt_) {
        int t = tc * 128 + tt_;
        const float* ur = u + (size_t)t * DIN;
        float acc = 0.f;
        #pragma unroll
        for (int k = 0; k < 64; ++k)
            acc = fmaf(Wt[k * 256 + tid], ur[k], acc);
        drive[(size_t)t * NH + i0 + tid] = acc;
    }
}

// ===== the scan: 64 blocks x 1024 thr, 32 rows/block, single-hop packed sync =====
__global__ __launch_bounds__(1024, 1) void scan_kernel(
    const float* __restrict__ W, const float* __restrict__ drive,
    float* __restrict__ X, u64* xpack)
{
    __shared__ float xls[NH];        // 8 KB
    const int tid     = threadIdx.x;
    const int r_local = tid >> 5;    // 32 rows/block, 32 lanes per row
    const int lane32  = tid & 31;
    const int row     = blockIdx.x * 32 + r_local;

    float4 wreg[16];                 // W[row][lane32*4 + 128j ..]
    {
        const float* wp = W + (size_t)row * NH + lane32 * 4;
        #pragma unroll
        for (int j = 0; j < 16; ++j) wreg[j] = *(const float4*)(wp + 128 * j);
    }

    for (int t = 0; t < TT; ++t) {
        float dval = drive[(size_t)t * NH + row];   // independent prefetch

        if (t == 0) {
            xls[tid] = 0.f; xls[tid + 1024] = 0.f;
        } else {
            const u64* src = xpack + (size_t)((t - 1) & 1) * NH;
            const int want = t;      // step t-1 published with epoch t
            u64 a = aload(&src[tid]);
            u64 b = aload(&src[tid + 1024]);
            bool pa = true, pb = true;
            if (ep_of(a) >= want) { xls[tid] = val_of(a); pa = false; }
            if (ep_of(b) >= want) { xls[tid + 1024] = val_of(b); pb = false; }
            while (pa || pb) {
                __builtin_amdgcn_s_sleep(1);
                if (pa) { u64 v = aload(&src[tid]);
                          if (ep_of(v) >= want) { xls[tid] = val_of(v); pa = false; } }
                if (pb) { u64 v = aload(&src[tid + 1024]);
                          if (ep_of(v) >= want) { xls[tid + 1024] = val_of(v); pb = false; } }
            }
        }
        __syncthreads();

        float acc = 0.f;
        #pragma unroll
        for (int j = 0; j < 16; ++j) {
            float4 xv4 = *(const float4*)&xls[lane32 * 4 + 128 * j];
            float4 wv = wreg[j];
            acc = fmaf(wv.x, xv4.x, fmaf(wv.y, xv4.y,
                  fmaf(wv.z, xv4.z, fmaf(wv.w, xv4.w, acc))));
        }
        #pragma unroll
        for (int m = 16; m; m >>= 1) acc += __shfl_xor(acc, m);

        if (lane32 == 0) {
            float v = tanhf(acc + dval);
            X[(size_t)t * NH + row] = v;                 // for gram/bvec/out
            astore(&xpack[(size_t)(t & 1) * NH + row], pack_ev(t + 1, v));
        }
        __syncthreads();
    }
}

// ===== A = Xw^T Xw + lambda*I : upper-triangle blocks only, mirrored =====
__global__ __launch_bounds__(256) void gram_kernel(
    const float* __restrict__ X, float* __restrict__ A)
{
    if (blockIdx.x < blockIdx.y) return;   // symmetry
    __shared__ float As[16 * 64];
    __shared__ float Bs[16 * 64];
    const int tx = threadIdx.x, ty = threadIdx.y;
    const int tid = ty * 16 + tx;
    const int i0 = blockIdx.y * 64, j0 = blockIdx.x * 64;
    const int ty4 = ty * 4, tx4 = tx * 4;
    float acc[4][4] = {};

    const int nch = (TW + 15) / 16;
    for (int ch = 0; ch < nch; ++ch) {
        int tbase = WASH + ch * 16;
        for (int v = tid; v < 16 * 64; v += 256) {
            int kk = v >> 6, col = v & 63;
            int t = tbase + kk;
            float a_ = 0.f, b_ = 0.f;
            if (t < TT) {
                a_ = X[(size_t)t * NH + i0 + col];
                b_ = X[(size_t)t * NH + j0 + col];
            }
            As[v] = a_; Bs[v] = b_;
        }
        __syncthreads();
        #pragma unroll
        for (int k = 0; k < 16; ++k) {
            float4 av = *(const float4*)&As[k * 64 + ty4];
            float4 bv = *(const float4*)&Bs[k * 64 + tx4];
            float a[4] = {av.x, av.y, av.z, av.w};
            float b[4] = {bv.x, bv.y, bv.z, bv.w};
            #pragma unroll
            for (int ai = 0; ai < 4; ++ai)
                #pragma unroll
                for (int bi = 0; bi < 4; ++bi)
                    acc[ai][bi] = fmaf(a[ai], b[bi], acc[ai][bi]);
        }
        __syncthreads();
    }
    const bool diag = (blockIdx.x == blockIdx.y);
    #pragma unroll
    for (int ai = 0; ai < 4; ++ai) {
        int gi = i0 + ty4 + ai;
        #pragma unroll
        for (int bi = 0; bi < 4; ++bi) {
            int gj = j0 + tx4 + bi;
            float v = acc[ai][bi];
            if (gi == gj) v += LAMBDA;
            A[(size_t)gi * NH + gj] = v;
            if (!diag) A[(size_t)gj * NH + gi] = v;
        }
    }
}

// ===== b = Xw^T yw : 64 blocks (8 i-chunks x 8 t-chunks) =====
__global__ void bvec_kernel(const float* __restrict__ X, const float* __restrict__ y,
                            float* __restrict__ bv)
{
    const int ic = blockIdx.x & 7, tc = blockIdx.x >> 3;
    const int i = ic * 256 + threadIdx.x;
    const int t0 = WASH + tc * (TW / 8), t1 = t0 + (TW / 8);
    float acc = 0.f;
    for (int t = t0; t < t1; ++t)
        acc = fmaf(X[(size_t)t * NH + i], y[t], acc);
    atomicAdd(&bv[i], acc);
}

__global__ void invdiag_kernel(const float* __restrict__ A, float* __restrict__ invd)
{
    int i = blockIdx.x * 256 + threadIdx.x;
    invd[i] = 1.0f / A[(size_t)i * NH + i];
}

// ===== truth-based two-phase Jacobi-PCG, 64 blocks x 1024 thr =====
// Exact R3 math (rho = (r,z) recomputed every iter — self-correcting on the
// ill-conditioned Gram; the C-G recurrence diverged in R4). A slice in VGPRs.
__global__ __launch_bounds__(1024, 1) void cg_kernel(
    const float* __restrict__ A, const float* __restrict__ bvec,
    const float* __restrict__ invd, float* __restrict__ xv,
    u64* ppack, u64* pqslot, u64* rzslot)
{
    __shared__ float pls[NH];        // 8 KB
    __shared__ float qsh[32], r32[32], x32[32], z32[32], inv32[32];
    __shared__ float csh[2];
    const int tid     = threadIdx.x;
    const int r_local = tid >> 5;
    const int lane32  = tid & 31;
    const int row0 = blockIdx.x * 32;
    const int row  = row0 + r_local;

    float4 areg[16];                 // A[row][lane32*4 + 128j ..] resident
    {
        const float* ap = A + (size_t)row * NH + lane32 * 4;
        #pragma unroll
        for (int j = 0; j < 16; ++j) areg[j] = *(const float4*)(ap + 128 * j);
    }

    // init: x=0, r=b, z=M^-1 r, p=z (epoch 1); rho0 = (r,z) via rzslot epoch 1
    if (tid < 32) {
        int i = row0 + tid;
        float bi = bvec[i], iv = invd[i];
        inv32[tid] = iv;
        x32[tid] = 0.f; r32[tid] = bi;
        float zi = iv * bi;
        z32[tid] = zi;
        astore(&ppack[i], pack_ev(1, zi));
        float part = bi * zi;
        #pragma unroll
        for (int m = 16; m; m >>= 1) part += __shfl_xor(part, m, 32);
        if (tid == 0) astore(&rzslot[blockIdx.x], pack_ev(1, part));
    }
    if (tid < 64) {     // wave 0: post (above) then poll — in-order within the wave
        u64 v = aload(&rzslot[tid]);
        while (ep_of(v) < 1) { __builtin_amdgcn_s_sleep(1); v = aload(&rzslot[tid]); }
        float s = val_of(v);
        #pragma unroll
        for (int m = 32; m; m >>= 1) s += __shfl_xor(s, m);
        if (tid == 0) csh[1] = s;
    }
    __syncthreads();
    float rho = csh[1];   // identical in all blocks (same slots, same order)

    for (int it = 0; it < CG_ITERS; ++it) {
        // gather p (epoch it+1), 2 words/thread
        {
            const int want = it + 1;
            u64 a = aload(&ppack[tid]);
            u64 b = aload(&ppack[tid + 1024]);
            bool pa = true, pb = true;
            if (ep_of(a) >= want) { pls[tid] = val_of(a); pa = false; }
            if (ep_of(b) >= want) { pls[tid + 1024] = val_of(b); pb = false; }
            while (pa || pb) {
                __builtin_amdgcn_s_sleep(1);
                if (pa) { u64 v = aload(&ppack[tid]);
                          if (ep_of(v) >= want) { pls[tid] = val_of(v); pa = false; } }
                if (pb) { u64 v = aload(&ppack[tid + 1024]);
                          if (ep_of(v) >= want) { pls[tid + 1024] = val_of(v); pb = false; } }
            }
        }
        __syncthreads();

        // q = A p (this block's 32 rows)
        float acc = 0.f;
        #pragma unroll
        for (int j = 0; j < 16; ++j) {
            float4 pv = *(const float4*)&pls[lane32 * 4 + 128 * j];
            float4 av = areg[j];
            acc = fmaf(av.x, pv.x, fmaf(av.y, pv.y,
                  fmaf(av.z, pv.z, fmaf(av.w, pv.w, acc))));
        }
        #pragma unroll
        for (int m = 16; m; m >>= 1) acc += __shfl_xor(acc, m, 32);
        if (lane32 == 0) qsh[r_local] = acc;
        __syncthreads();

        // phase A: pq = (p,q) -> alpha
        if (tid < 32) {
            float t1 = qsh[tid] * pls[row0 + tid];
            #pragma unroll
            for (int m = 16; m; m >>= 1) t1 += __shfl_xor(t1, m, 32);
            if (tid == 0) astore(&pqslot[blockIdx.x], pack_ev(it + 1, t1));
        }
        if (tid < 64) {
            u64 v = aload(&pqslot[tid]);
            while (ep_of(v) < it + 1) { __builtin_amdgcn_s_sleep(1); v = aload(&pqslot[tid]); }
            float s = val_of(v);
            #pragma unroll
            for (int m = 32; m; m >>= 1) s += __shfl_xor(s, m);
            if (tid == 0) csh[0] = s;
        }
        __syncthreads();
        float pq = csh[0];
        float alpha = (pq != 0.f) ? rho / pq : 0.f;

        // phase B: update r,z; rho_new = (r,z) truth -> beta
        if (tid < 32) {
            int i = row0 + tid;
            float pi = pls[i], qi = qsh[tid];
            x32[tid] = fmaf(alpha, pi, x32[tid]);
            float ri = r32[tid] - alpha * qi;
            r32[tid] = ri;
            float zi = inv32[tid] * ri;
            z32[tid] = zi;
            float t2 = ri * zi;
            #pragma unroll
            for (int m = 16; m; m >>= 1) t2 += __shfl_xor(t2, m, 32);
            if (tid == 0) astore(&rzslot[blockIdx.x], pack_ev(it + 2, t2));
        }
        if (tid < 64) {
            u64 v = aload(&rzslot[tid]);
            while (ep_of(v) < it + 2) { __builtin_amdgcn_s_sleep(1); v = aload(&rzslot[tid]); }
            float s = val_of(v);
            #pragma unroll
            for (int m = 32; m; m >>= 1) s += __shfl_xor(s, m);
            if (tid == 0) csh[1] = s;
        }
        __syncthreads();
        float rho_new = csh[1];
        float beta = (rho != 0.f) ? rho_new / rho : 0.f;

        // p update (epoch it+2)
        if (tid < 32) {
            int i = row0 + tid;
            float pn = fmaf(beta, pls[i], z32[tid]);
            astore(&ppack[i], pack_ev(it + 2, pn));
        }
        rho = rho_new;
        __syncthreads();   // pls/qsh/csh stable until all uses done
    }

    if (tid < 32) xv[row0 + tid] = x32[tid];
}

// ===== out = Xw @ Wout =====
__global__ void out_kernel(const float* __restrict__ X, const float* __restrict__ w,
                           float* __restrict__ out)
{
    __shared__ float red[4];
    const int tid = threadIdx.x;
    const int rowt = WASH + blockIdx.x;
    float acc = 0.f;
    #pragma unroll
    for (int j = 0; j < 8; ++j) {
        int c = tid + 256 * j;
        acc = fmaf(X[(size_t)rowt * NH + c], w[c], acc);
    }
    #pragma unroll
    for (int m = 32; m; m >>= 1) acc += __shfl_xor(acc, m);
    if ((tid & 63) == 0) red[tid >> 6] = acc;
    __syncthreads();
    if (tid == 0) out[blockIdx.x] = red[0] + red[1] + red[2] + red[3];
}

extern "C" void kernel_launch(void* const* d_in, const int* in_sizes, int n_in,
                              void* d_out, int out_size, void* d_ws, size_t ws_size,
                              hipStream_t stream)
{
    const float* u    = (const float*)d_in[0];   // (4096, 64)
    const float* y    = (const float*)d_in[1];   // (4096, 1)
    const float* Win  = (const float*)d_in[2];   // (2048, 64)
    const float* Wres = (const float*)d_in[3];   // (2048, 2048)
    // d_in[4] = washout (==200), hardcoded as WASH

    float* ws = (float*)d_ws;
    float* X     = ws + X_OFF;
    float* drive = ws + DRIVE_OFF;
    float* A     = ws + A_OFF;
    u64*   ub    = (u64*)(ws + WS_FLOATS);
    u64*   xpack = ub + XPACK_OFF;
    u64*   ppack = ub + PPACK_OFF;
    u64*   pqslot = ub + PQSLOT_OFF;
    u64*   rzslot = ub + RZSLOT_OFF;

    init_kernel<<<1, 256, 0, stream>>>(ws);
    drive_kernel<<<256, 256, 0, stream>>>(u, Win, drive);
    scan_kernel<<<SCAN_BLOCKS, 1024, 0, stream>>>(Wres, drive, X, xpack);
    gram_kernel<<<dim3(32, 32), dim3(16, 16), 0, stream>>>(X, A);
    bvec_kernel<<<64, 256, 0, stream>>>(X, y, ws + B_OFF);
    invdiag_kernel<<<8, 256, 0, stream>>>(A, ws + INVD_OFF);
    cg_kernel<<<CG_BLOCKS, 1024, 0, stream>>>(A, ws + B_OFF, ws + INVD_OFF,
                                              ws + XV_OFF, ppack, pqslot, rzslot);
    out_kernel<<<TW, 256, 0, stream>>>(X, ws + XV_OFF, (float*)d_out);
}

// Round 6
// 13323.770 us; speedup vs baseline: 1.4045x; 1.0883x over previous
//
#include <hip/hip_runtime.h>
#include <math.h>

// ===== problem constants (washout hardcoded=200 per reference) =====
#define NH      2048
#define TT      4096
#define DIN     64
#define WASH    200
#define TW      (TT - WASH)      // 3896
#define LAMBDA  1e-6f

#define SCAN_BLOCKS  64          // 32 rows/block, 1024 threads (wave = 2 rows)
#define CG_BLOCKS    64
#define CG_ITERS     320

typedef unsigned long long u64;

// ===== workspace layout =====
// floats:
#define X_OFF      ((size_t)0)                 // TT*NH (32 MB)
#define DRIVE_OFF  ((size_t)TT * NH)           // TT*NH (dead after scan)
#define A_OFF      DRIVE_OFF                   // NH*NH aliases drive
#define B_OFF      ((size_t)2 * TT * NH)       // NH
#define INVD_OFF   (B_OFF + NH)                // NH
#define XV_OFF     (INVD_OFF + NH)             // NH (Wout)
#define WS_FLOATS  (XV_OFF + NH)               // even -> u64 area 8B-aligned
// u64s (at ws + WS_FLOATS):
#define XPACK_OFF  ((size_t)0)                 // 2*NH (double-buffered packed x)
#define ZPACK_OFF  ((size_t)2 * NH)            // NH   (packed z for CG)
#define PQSLOT_OFF ((size_t)3 * NH)            // 64   ((p,q) partials)
#define RZSLOT_OFF ((size_t)3 * NH + 64)       // 64   ((r,z) partials)
#define U64_TOTAL  ((size_t)3 * NH + 128)

__device__ __forceinline__ u64 pack_ev(int epoch, float v) {
    return ((u64)(unsigned)epoch << 32) | (u64)__float_as_uint(v);
}
__device__ __forceinline__ int   ep_of(u64 p)  { return (int)(p >> 32); }
__device__ __forceinline__ float val_of(u64 p) { return __uint_as_float((unsigned)p); }

__device__ __forceinline__ u64 aload(const u64* p) {
    return __hip_atomic_load(p, __ATOMIC_RELAXED, __HIP_MEMORY_SCOPE_AGENT);
}
__device__ __forceinline__ void astore(u64* p, u64 v) {
    __hip_atomic_store(p, v, __ATOMIC_RELAXED, __HIP_MEMORY_SCOPE_AGENT);
}

// ===== init =====
__global__ void init_kernel(float* ws) {
    int tid = threadIdx.x;
    u64* ub = (u64*)(ws + WS_FLOATS);
    for (size_t i = tid; i < U64_TOTAL; i += 256) ub[i] = 0ull;
    for (int i = tid; i < NH; i += 256) ws[B_OFF + i] = 0.f;
}

// ===== drive = u @ W_in.T =====
__global__ __launch_bounds__(256) void drive_kernel(
    const float* __restrict__ u, const float* __restrict__ Win,
    float* __restrict__ drive)
{
    __shared__ float Wt[256 * 64];
    const int tid = threadIdx.x;
    const int ic = blockIdx.x & 7;
    const int tc = blockIdx.x >> 3;
    const int i0 = ic * 256;
    for (int idx = tid; idx < 256 * 64; idx += 256) {
        int il = idx >> 6, k = idx & 63;
        Wt[k * 256 + il] = Win[(size_t)i0 * 64 + idx];
    }
    __syncthreads();
    for (int tt_ = 0; tt_ < 128; ++tt_) {
        int t = tc * 128 + tt_;
        const float* ur = u + (size_t)t * DIN;
        float acc = 0.f;
        #pragma unroll
        for (int k = 0; k < 64; ++k)
            acc = fmaf(Wt[k * 256 + tid], ur[k], acc);
        drive[(size_t)t * NH + i0 + tid] = acc;
    }
}

// ===== the scan: 64 blocks x 1024 thr; wave w owns rows {2w,2w+1} =====
// Per thread: 8 x ds_read_b128 (32 floats) feeding 2 rows -> LDS traffic
// halved vs 1-row-per-32-lanes mapping. Packed-epoch single-hop sync.
__global__ __launch_bounds__(1024, 1) void scan_kernel(
    const float* __restrict__ W, const float* __restrict__ drive,
    float* __restrict__ X, u64* xpack)
{
    __shared__ float xls[NH];        // 8 KB
    const int tid  = threadIdx.x;
    const int wave = tid >> 6;       // 16 waves
    const int lane = tid & 63;
    const int rowA = blockIdx.x * 32 + wave * 2;   // rows rowA, rowA+1

    // W fragments: cols = lane*4 + 256*j, two rows
    float4 wA[8], wB[8];
    {
        const float* wpA = W + (size_t)rowA * NH + lane * 4;
        const float* wpB = wpA + NH;
        #pragma unroll
        for (int j = 0; j < 8; ++j) {
            wA[j] = *(const float4*)(wpA + 256 * j);
            wB[j] = *(const float4*)(wpB + 256 * j);
        }
    }

    for (int t = 0; t < TT; ++t) {
        float dval = (lane < 2) ? drive[(size_t)t * NH + rowA + lane] : 0.f;

        if (t == 0) {
            xls[tid] = 0.f; xls[tid + 1024] = 0.f;
        } else {
            const u64* src = xpack + (size_t)((t - 1) & 1) * NH;
            const int want = t;      // step t-1 published with epoch t
            u64 a = aload(&src[tid]);
            u64 b = aload(&src[tid + 1024]);
            bool pa = true, pb = true;
            if (ep_of(a) >= want) { xls[tid] = val_of(a); pa = false; }
            if (ep_of(b) >= want) { xls[tid + 1024] = val_of(b); pb = false; }
            while (pa || pb) {
                __builtin_amdgcn_s_sleep(1);
                if (pa) { u64 v = aload(&src[tid]);
                          if (ep_of(v) >= want) { xls[tid] = val_of(v); pa = false; } }
                if (pb) { u64 v = aload(&src[tid + 1024]);
                          if (ep_of(v) >= want) { xls[tid + 1024] = val_of(v); pb = false; } }
            }
        }
        __syncthreads();

        float a0 = 0.f, a1 = 0.f;
        #pragma unroll
        for (int j = 0; j < 8; ++j) {
            float4 xv = *(const float4*)&xls[lane * 4 + 256 * j];
            float4 va = wA[j], vb = wB[j];
            a0 = fmaf(va.x, xv.x, fmaf(va.y, xv.y, fmaf(va.z, xv.z, fmaf(va.w, xv.w, a0))));
            a1 = fmaf(vb.x, xv.x, fmaf(vb.y, xv.y, fmaf(vb.z, xv.z, fmaf(vb.w, xv.w, a1))));
        }
        #pragma unroll
        for (int m = 32; m; m >>= 1) { a0 += __shfl_xor(a0, m); a1 += __shfl_xor(a1, m); }

        if (lane < 2) {
            float acc = (lane == 0) ? a0 : a1;
            int row = rowA + lane;
            float v = tanhf(acc + dval);
            X[(size_t)t * NH + row] = v;                 // for gram/bvec/out
            astore(&xpack[(size_t)(t & 1) * NH + row], pack_ev(t + 1, v));
        }
        __syncthreads();   // xls stable until all reads done
    }
}

// ===== A = Xw^T Xw + lambda*I : upper-triangle blocks only, mirrored =====
__global__ __launch_bounds__(256) void gram_kernel(
    const float* __restrict__ X, float* __restrict__ A)
{
    if (blockIdx.x < blockIdx.y) return;   // symmetry
    __shared__ float As[16 * 64];
    __shared__ float Bs[16 * 64];
    const int tx = threadIdx.x, ty = threadIdx.y;
    const int tid = ty * 16 + tx;
    const int i0 = blockIdx.y * 64, j0 = blockIdx.x * 64;
    const int ty4 = ty * 4, tx4 = tx * 4;
    float acc[4][4] = {};

    const int nch = (TW + 15) / 16;
    for (int ch = 0; ch < nch; ++ch) {
        int tbase = WASH + ch * 16;
        for (int v = tid; v < 16 * 64; v += 256) {
            int kk = v >> 6, col = v & 63;
            int t = tbase + kk;
            float a_ = 0.f, b_ = 0.f;
            if (t < TT) {
                a_ = X[(size_t)t * NH + i0 + col];
                b_ = X[(size_t)t * NH + j0 + col];
            }
            As[v] = a_; Bs[v] = b_;
        }
        __syncthreads();
        #pragma unroll
        for (int k = 0; k < 16; ++k) {
            float4 av = *(const float4*)&As[k * 64 + ty4];
            float4 bv = *(const float4*)&Bs[k * 64 + tx4];
            float a[4] = {av.x, av.y, av.z, av.w};
            float b[4] = {bv.x, bv.y, bv.z, bv.w};
            #pragma unroll
            for (int ai = 0; ai < 4; ++ai)
                #pragma unroll
                for (int bi = 0; bi < 4; ++bi)
                    acc[ai][bi] = fmaf(a[ai], b[bi], acc[ai][bi]);
        }
        __syncthreads();
    }
    const bool diag = (blockIdx.x == blockIdx.y);
    #pragma unroll
    for (int ai = 0; ai < 4; ++ai) {
        int gi = i0 + ty4 + ai;
        #pragma unroll
        for (int bi = 0; bi < 4; ++bi) {
            int gj = j0 + tx4 + bi;
            float v = acc[ai][bi];
            if (gi == gj) v += LAMBDA;
            A[(size_t)gi * NH + gj] = v;
            if (!diag) A[(size_t)gj * NH + gi] = v;
        }
    }
}

// ===== b = Xw^T yw : 64 blocks (8 i-chunks x 8 t-chunks) =====
__global__ void bvec_kernel(const float* __restrict__ X, const float* __restrict__ y,
                            float* __restrict__ bv)
{
    const int ic = blockIdx.x & 7, tc = blockIdx.x >> 3;
    const int i = ic * 256 + threadIdx.x;
    const int t0 = WASH + tc * (TW / 8), t1 = t0 + (TW / 8);
    float acc = 0.f;
    for (int t = t0; t < t1; ++t)
        acc = fmaf(X[(size_t)t * NH + i], y[t], acc);
    atomicAdd(&bv[i], acc);
}

__global__ void invdiag_kernel(const float* __restrict__ A, float* __restrict__ invd)
{
    int i = blockIdx.x * 256 + threadIdx.x;
    invd[i] = 1.0f / A[(size_t)i * NH + i];
}

// ===== truth-based Jacobi-PCG, 2 visibility phases/iter =====
// Publish z (+rz partials); every block reconstructs p = z + beta*p locally
// from its persistent LDS copy (beta deterministic from identical slot data),
// so p never crosses blocks. Then q = A p (own rows) -> pq partials (2nd
// phase) -> alpha -> own x,r,z updates -> publish z. rho = (r,z) truth.
__global__ __launch_bounds__(1024, 1) void cg_kernel(
    const float* __restrict__ A, const float* __restrict__ bvec,
    const float* __restrict__ invd, float* __restrict__ xv,
    u64* zpack, u64* pqslot, u64* rzslot)
{
    __shared__ float pls[NH];        // persistent p (8 KB)
    __shared__ float zls[NH];        // gathered z  (8 KB)
    __shared__ float r32[32], x32[32], q32[32], inv32[32];
    __shared__ float csh[2];
    const int tid     = threadIdx.x;
    const int r_local = tid >> 5;
    const int lane32  = tid & 31;
    const int row0 = blockIdx.x * 32;
    const int row  = row0 + r_local;

    float4 areg[16];                 // A[row][lane32*4 + 128j ..] resident
    {
        const float* ap = A + (size_t)row * NH + lane32 * 4;
        #pragma unroll
        for (int j = 0; j < 16; ++j) areg[j] = *(const float4*)(ap + 128 * j);
    }

    pls[tid] = 0.f; pls[tid + 1024] = 0.f;

    // init: x=0, r=b, z=M^-1 r; publish z (epoch 1) + rz partial (epoch 1)
    if (tid < 32) {
        int i = row0 + tid;
        float bi = bvec[i], iv = invd[i];
        inv32[tid] = iv;
        x32[tid] = 0.f; r32[tid] = bi;
        float zi = iv * bi;
        astore(&zpack[i], pack_ev(1, zi));
        float part = bi * zi;
        #pragma unroll
        for (int m = 16; m; m >>= 1) part += __shfl_xor(part, m, 32);
        if (tid == 0) astore(&rzslot[blockIdx.x], pack_ev(1, part));
    }
    __syncthreads();

    float rho_prev = 1.f;

    for (int it = 0; it < CG_ITERS; ++it) {
        // --- phase 1: gather z (epoch it+1) + rz slots -> rho, beta ---
        {
            const int want = it + 1;
            u64 a = aload(&zpack[tid]);
            u64 b = aload(&zpack[tid + 1024]);
            bool pa = true, pb = true;
            if (ep_of(a) >= want) { zls[tid] = val_of(a); pa = false; }
            if (ep_of(b) >= want) { zls[tid + 1024] = val_of(b); pb = false; }
            while (pa || pb) {
                __builtin_amdgcn_s_sleep(1);
                if (pa) { u64 v = aload(&zpack[tid]);
                          if (ep_of(v) >= want) { zls[tid] = val_of(v); pa = false; } }
                if (pb) { u64 v = aload(&zpack[tid + 1024]);
                          if (ep_of(v) >= want) { zls[tid + 1024] = val_of(v); pb = false; } }
            }
        }
        if (tid < 64) {
            u64 v = aload(&rzslot[tid]);
            while (ep_of(v) < it + 1) { __builtin_amdgcn_s_sleep(1); v = aload(&rzslot[tid]); }
            float s = val_of(v);
            #pragma unroll
            for (int m = 32; m; m >>= 1) s += __shfl_xor(s, m);
            if (tid == 0) csh[1] = s;
        }
        __syncthreads();
        float rho = csh[1];
        float beta = (it == 0) ? 0.f : ((rho_prev != 0.f) ? rho / rho_prev : 0.f);

        // --- p = z + beta*p (full vector, locally; identical in all blocks) ---
        pls[tid]        = fmaf(beta, pls[tid],        zls[tid]);
        pls[tid + 1024] = fmaf(beta, pls[tid + 1024], zls[tid + 1024]);
        __syncthreads();

        // --- q = A p (own 32 rows) ---
        float acc = 0.f;
        #pragma unroll
        for (int j = 0; j < 16; ++j) {
            float4 pv = *(const float4*)&pls[lane32 * 4 + 128 * j];
            float4 av = areg[j];
            acc = fmaf(av.x, pv.x, fmaf(av.y, pv.y,
                  fmaf(av.z, pv.z, fmaf(av.w, pv.w, acc))));
        }
        #pragma unroll
        for (int m = 16; m; m >>= 1) acc += __shfl_xor(acc, m, 32);
        if (lane32 == 0) q32[r_local] = acc;
        __syncthreads();

        // --- phase 2: pq partial -> alpha ---
        if (tid < 32) {
            float t1 = q32[tid] * pls[row0 + tid];
            #pragma unroll
            for (int m = 16; m; m >>= 1) t1 += __shfl_xor(t1, m, 32);
            if (tid == 0) astore(&pqslot[blockIdx.x], pack_ev(it + 1, t1));
        }
        if (tid < 64) {
            u64 v = aload(&pqslot[tid]);
            while (ep_of(v) < it + 1) { __builtin_amdgcn_s_sleep(1); v = aload(&pqslot[tid]); }
            float s = val_of(v);
            #pragma unroll
            for (int m = 32; m; m >>= 1) s += __shfl_xor(s, m);
            if (tid == 0) csh[0] = s;
        }
        __syncthreads();
        float pq = csh[0];
        float alpha = (pq != 0.f) ? rho / pq : 0.f;

        // --- own updates; publish z (epoch it+2) + rz partial ---
        if (tid < 32) {
            int i = row0 + tid;
            float pi = pls[i], qi = q32[tid];
            x32[tid] = fmaf(alpha, pi, x32[tid]);
            float ri = r32[tid] - alpha * qi;
            r32[tid] = ri;
            float zi = inv32[tid] * ri;
            astore(&zpack[i], pack_ev(it + 2, zi));
            float t2 = ri * zi;
            #pragma unroll
            for (int m = 16; m; m >>= 1) t2 += __shfl_xor(t2, m, 32);
            if (tid == 0) astore(&rzslot[blockIdx.x], pack_ev(it + 2, t2));
        }
        rho_prev = rho;
        __syncthreads();   // csh/zls/pls stable until all uses done
    }

    if (tid < 32) xv[row0 + tid] = x32[tid];
}

// ===== out = Xw @ Wout =====
__global__ void out_kernel(const float* __restrict__ X, const float* __restrict__ w,
                           float* __restrict__ out)
{
    __shared__ float red[4];
    const int tid = threadIdx.x;
    const int rowt = WASH + blockIdx.x;
    float acc = 0.f;
    #pragma unroll
    for (int j = 0; j < 8; ++j) {
        int c = tid + 256 * j;
        acc = fmaf(X[(size_t)rowt * NH + c], w[c], acc);
    }
    #pragma unroll
    for (int m = 32; m; m >>= 1) acc += __shfl_xor(acc, m);
    if ((tid & 63) == 0) red[tid >> 6] = acc;
    __syncthreads();
    if (tid == 0) out[blockIdx.x] = red[0] + red[1] + red[2] + red[3];
}

extern "C" void kernel_launch(void* const* d_in, const int* in_sizes, int n_in,
                              void* d_out, int out_size, void* d_ws, size_t ws_size,
                              hipStream_t stream)
{
    const float* u    = (const float*)d_in[0];   // (4096, 64)
    const float* y    = (const float*)d_in[1];   // (4096, 1)
    const float* Win  = (const float*)d_in[2];   // (2048, 64)
    const float* Wres = (const float*)d_in[3];   // (2048, 2048)
    // d_in[4] = washout (==200), hardcoded as WASH

    float* ws = (float*)d_ws;
    float* X     = ws + X_OFF;
    float* drive = ws + DRIVE_OFF;
    float* A     = ws + A_OFF;
    u64*   ub    = (u64*)(ws + WS_FLOATS);
    u64*   xpack  = ub + XPACK_OFF;
    u64*   zpack  = ub + ZPACK_OFF;
    u64*   pqslot = ub + PQSLOT_OFF;
    u64*   rzslot = ub + RZSLOT_OFF;

    init_kernel<<<1, 256, 0, stream>>>(ws);
    drive_kernel<<<256, 256, 0, stream>>>(u, Win, drive);
    scan_kernel<<<SCAN_BLOCKS, 1024, 0, stream>>>(Wres, drive, X, xpack);
    gram_kernel<<<dim3(32, 32), dim3(16, 16), 0, stream>>>(X, A);
    bvec_kernel<<<64, 256, 0, stream>>>(X, y, ws + B_OFF);
    invdiag_kernel<<<8, 256, 0, stream>>>(A, ws + INVD_OFF);
    cg_kernel<<<CG_BLOCKS, 1024, 0, stream>>>(A, ws + B_OFF, ws + INVD_OFF,
                                              ws + XV_OFF, zpack, pqslot, rzslot);
    out_kernel<<<TW, 256, 0, stream>>>(X, ws + XV_OFF, (float*)d_out);
}